// Round 1
// baseline (826.871 us; speedup 1.0000x reference)
//
#include <hip/hip_runtime.h>

// RGCN 2-layer: N=50000 nodes, E=800000 edges, R=8 relations, 64->64->32.
// fp32 throughout (no fp32 MFMA on CDNA4; vector ALU).
// Pipeline: memset cnt -> hist -> inv -> root1 -> edge1 -> root2 -> edge2.

#define NN 50000
#define NE 800000
#define NR 8

__device__ __forceinline__ float bcast(int xi, int f) {
  // wave-wide broadcast of lane f's value (f wave-uniform): v_readlane -> sgpr
  return __int_as_float(__builtin_amdgcn_readlane(xi, f));
}

// ---- per-(dst,rel) incoming-edge count --------------------------------------
__global__ __launch_bounds__(256) void k_hist(const int* __restrict__ dst,
                                              const int* __restrict__ et,
                                              int* __restrict__ cnt) {
  int e = blockIdx.x * 256 + threadIdx.x;
  if (e < NE) atomicAdd(&cnt[dst[e] * NR + et[e]], 1);
}

// in-place int count -> float 1/max(cnt,1)
__global__ __launch_bounds__(256) void k_inv(int* __restrict__ cnt) {
  int i = blockIdx.x * 256 + threadIdx.x;
  if (i < NN * NR) {
    int c = cnt[i];
    if (c < 1) c = 1;
    ((float*)cnt)[i] = 1.0f / (float)c;
  }
}

// ---- layer-1 root: buf1 = x @ root1 + b1  (wave per node) -------------------
__global__ __launch_bounds__(256) void k_root1(const float* __restrict__ x,
                                               const float* __restrict__ root1,
                                               const float* __restrict__ b1,
                                               float* __restrict__ buf1) {
  const int lane = threadIdx.x & 63;
  const int wid  = (blockIdx.x * 256 + (int)threadIdx.x) >> 6;
  const int nw   = gridDim.x * 4;
  float w[64];
#pragma unroll
  for (int f = 0; f < 64; ++f) w[f] = root1[f * 64 + lane];  // column `lane`
  const float bl = b1[lane];
  for (int n = wid; n < NN; n += nw) {
    const int xi = __float_as_int(x[n * 64 + lane]);
    float a0 = bl, a1 = 0.f, a2 = 0.f, a3 = 0.f;
#pragma unroll
    for (int f = 0; f < 64; f += 4) {
      a0 = fmaf(bcast(xi, f + 0), w[f + 0], a0);
      a1 = fmaf(bcast(xi, f + 1), w[f + 1], a1);
      a2 = fmaf(bcast(xi, f + 2), w[f + 2], a2);
      a3 = fmaf(bcast(xi, f + 3), w[f + 3], a3);
    }
    buf1[n * 64 + lane] = (a0 + a1) + (a2 + a3);
  }
}

// ---- layer-1 edges: buf1[dst] += (x[src] @ W1[r]) / cnt[dst,r] --------------
// gridDim.y = relation; W1[r] column `lane` lives in 64 VGPRs; ballot-compact
// the 64-edge chunk, whole wave does one matvec per matching edge.
__global__ __launch_bounds__(256) void k_edge1(const float* __restrict__ x,
                                               const int* __restrict__ ei,
                                               const int* __restrict__ et,
                                               const float* __restrict__ W1,
                                               const float* __restrict__ inv,
                                               float* __restrict__ buf1) {
  const int r    = blockIdx.y;
  const int lane = threadIdx.x & 63;
  float w[64];
#pragma unroll
  for (int f = 0; f < 64; ++f) w[f] = W1[r * 4096 + f * 64 + lane];
  const int* __restrict__ srcA = ei;       // edge_index[0,:]
  const int* __restrict__ dstA = ei + NE;  // edge_index[1,:]
  const int wir = blockIdx.x * 4 + ((int)threadIdx.x >> 6);
  const int wpr = gridDim.x * 4;
  const int nch = (NE + 63) >> 6;
  for (int c = wir; c < nch; c += wpr) {
    const int e = c * 64 + lane;
    int sv = 0, dv = 0, tv = -1;
    if (e < NE) { sv = srcA[e]; dv = dstA[e]; tv = et[e]; }
    unsigned long long m = __ballot(tv == r);
    while (m) {
      const int i = __builtin_ctzll(m);
      m &= m - 1;
      const int s = __builtin_amdgcn_readlane(sv, i);
      const int d = __builtin_amdgcn_readlane(dv, i);
      const int xi = __float_as_int(x[s * 64 + lane]);
      float a0 = 0.f, a1 = 0.f, a2 = 0.f, a3 = 0.f;
#pragma unroll
      for (int f = 0; f < 64; f += 4) {
        a0 = fmaf(bcast(xi, f + 0), w[f + 0], a0);
        a1 = fmaf(bcast(xi, f + 1), w[f + 1], a1);
        a2 = fmaf(bcast(xi, f + 2), w[f + 2], a2);
        a3 = fmaf(bcast(xi, f + 3), w[f + 3], a3);
      }
      const float sc = inv[d * NR + r];
      atomicAdd(&buf1[d * 64 + lane], ((a0 + a1) + (a2 + a3)) * sc);
    }
  }
}

// ---- layer-2 root: out = relu(buf1) @ root2 + b2  (wave per node) -----------
// 64 lanes cover 32 outputs x 2 f-halves; combine halves with shfl_down(32).
__global__ __launch_bounds__(256) void k_root2(const float* __restrict__ buf1,
                                               const float* __restrict__ root2,
                                               const float* __restrict__ b2,
                                               float* __restrict__ out) {
  const int lane = threadIdx.x & 63;
  const int o  = lane & 31;
  const int fh = lane >> 5;
  const int wid = (blockIdx.x * 256 + (int)threadIdx.x) >> 6;
  const int nw  = gridDim.x * 4;
  float w[32];
#pragma unroll
  for (int k = 0; k < 32; ++k) w[k] = root2[(fh * 32 + k) * 32 + o];
  const float bo = b2[o];
  for (int n = wid; n < NN; n += nw) {
    const int xi = __float_as_int(fmaxf(buf1[n * 64 + lane], 0.f));
    float a0 = 0.f, a1 = 0.f;
#pragma unroll
    for (int k = 0; k < 32; k += 2) {
      float lo0 = bcast(xi, k),     hi0 = bcast(xi, 32 + k);
      float lo1 = bcast(xi, k + 1), hi1 = bcast(xi, 33 + k);
      a0 = fmaf(fh ? hi0 : lo0, w[k], a0);
      a1 = fmaf(fh ? hi1 : lo1, w[k + 1], a1);
    }
    float acc = a0 + a1;
    float oth = __shfl_down(acc, 32);
    if (fh == 0) out[n * 32 + o] = acc + oth + bo;
  }
}

// ---- layer-2 edges: out[dst] += (relu(buf1[src]) @ W2[r]) / cnt[dst,r] ------
__global__ __launch_bounds__(256) void k_edge2(const float* __restrict__ buf1,
                                               const int* __restrict__ ei,
                                               const int* __restrict__ et,
                                               const float* __restrict__ W2,
                                               const float* __restrict__ inv,
                                               float* __restrict__ out) {
  const int r    = blockIdx.y;
  const int lane = threadIdx.x & 63;
  const int o  = lane & 31;
  const int fh = lane >> 5;
  float w[32];
#pragma unroll
  for (int k = 0; k < 32; ++k) w[k] = W2[r * 2048 + (fh * 32 + k) * 32 + o];
  const int* __restrict__ srcA = ei;
  const int* __restrict__ dstA = ei + NE;
  const int wir = blockIdx.x * 4 + ((int)threadIdx.x >> 6);
  const int wpr = gridDim.x * 4;
  const int nch = (NE + 63) >> 6;
  for (int c = wir; c < nch; c += wpr) {
    const int e = c * 64 + lane;
    int sv = 0, dv = 0, tv = -1;
    if (e < NE) { sv = srcA[e]; dv = dstA[e]; tv = et[e]; }
    unsigned long long m = __ballot(tv == r);
    while (m) {
      const int i = __builtin_ctzll(m);
      m &= m - 1;
      const int s = __builtin_amdgcn_readlane(sv, i);
      const int d = __builtin_amdgcn_readlane(dv, i);
      const int xi = __float_as_int(fmaxf(buf1[s * 64 + lane], 0.f));
      float a0 = 0.f, a1 = 0.f;
#pragma unroll
      for (int k = 0; k < 32; k += 2) {
        float lo0 = bcast(xi, k),     hi0 = bcast(xi, 32 + k);
        float lo1 = bcast(xi, k + 1), hi1 = bcast(xi, 33 + k);
        a0 = fmaf(fh ? hi0 : lo0, w[k], a0);
        a1 = fmaf(fh ? hi1 : lo1, w[k + 1], a1);
      }
      float acc = a0 + a1;
      float oth = __shfl_down(acc, 32);
      if (fh == 0) {
        const float sc = inv[d * NR + r];
        atomicAdd(&out[d * 32 + o], (acc + oth) * sc);
      }
    }
  }
}

extern "C" void kernel_launch(void* const* d_in, const int* in_sizes, int n_in,
                              void* d_out, int out_size, void* d_ws, size_t ws_size,
                              hipStream_t stream) {
  const float* x     = (const float*)d_in[0];
  const int*   ei    = (const int*)d_in[1];  // [2, E] int32
  const int*   et    = (const int*)d_in[2];  // [E]    int32
  const float* W1    = (const float*)d_in[3];
  const float* root1 = (const float*)d_in[4];
  const float* b1    = (const float*)d_in[5];
  const float* W2    = (const float*)d_in[6];
  const float* root2 = (const float*)d_in[7];
  const float* b2    = (const float*)d_in[8];
  float* out = (float*)d_out;

  // ws layout: [cnt/inv: N*R*4 = 1.6MB][buf1: N*64*4 = 12.8MB]
  int*   cnt  = (int*)d_ws;
  float* inv  = (float*)d_ws;
  float* buf1 = (float*)((char*)d_ws + (size_t)NN * NR * 4);

  hipMemsetAsync(cnt, 0, (size_t)NN * NR * 4, stream);
  k_hist<<<(NE + 255) / 256, 256, 0, stream>>>(ei + NE, et, cnt);
  k_inv<<<(NN * NR + 255) / 256, 256, 0, stream>>>(cnt);
  k_root1<<<1024, 256, 0, stream>>>(x, root1, b1, buf1);
  k_edge1<<<dim3(128, NR), 256, 0, stream>>>(x, ei, et, W1, inv, buf1);
  k_root2<<<512, 256, 0, stream>>>(buf1, root2, b2, out);
  k_edge2<<<dim3(128, NR), 256, 0, stream>>>(buf1, ei, et, W2, inv, out);
}

// Round 2
// 515.884 us; speedup vs baseline: 1.6028x; 1.6028x over previous
//
#include <hip/hip_runtime.h>

// RGCN 2-layer: N=50000, E=800000, R=8, 64->64->32, fp32.
// Fast path (needs ~121MB ws):
//   hist -> inv+cntd -> scan -> scatter(CSR by dst) ->
//   root1 -> h1[r]=x@W1[r] (dense) -> agg1 (gather, no atomics) ->
//   root2 -> h2[r]=relu(buf1)@W2[r] -> agg2 (gather)
// Fallback (ws < REQ): R1 ballot-compact edge kernels (~14.4MB ws).

#define NN 50000
#define NE 800000
#define NR 8

__device__ __forceinline__ float bcast(int xi, int f) {
  return __int_as_float(__builtin_amdgcn_readlane(xi, f));
}

// ---- per-(dst,rel) incoming-edge count --------------------------------------
__global__ __launch_bounds__(256) void k_hist(const int* __restrict__ dst,
                                              const int* __restrict__ et,
                                              int* __restrict__ cnt) {
  int e = blockIdx.x * 256 + threadIdx.x;
  if (e < NE) atomicAdd(&cnt[dst[e] * NR + et[e]], 1);
}

// cnt -> inv (in place, float) + per-dst total count
__global__ __launch_bounds__(256) void k_inv2(int* __restrict__ cnt,
                                              int* __restrict__ cntd) {
  int n = blockIdx.x * 256 + threadIdx.x;
  if (n < NN) {
    float* invp = (float*)cnt;
    int s = 0;
#pragma unroll
    for (int r = 0; r < NR; ++r) {
      int c = cnt[n * NR + r];
      s += c;
      invp[n * NR + r] = 1.0f / (float)(c < 1 ? 1 : c);
    }
    cntd[n] = s;
  }
}

// single-block exclusive scan of cntd[NN] -> rowptr, cursor
__global__ __launch_bounds__(1024) void k_scan(const int* __restrict__ cntd,
                                               int* __restrict__ rowptr,
                                               int* __restrict__ cursor) {
  __shared__ int ps[1024];
  const int t = threadIdx.x;
  const int CH = (NN + 1023) / 1024;
  int lo = t * CH, hi = lo + CH;
  if (hi > NN) hi = NN;
  int s = 0;
  for (int i = lo; i < hi; ++i) s += cntd[i];
  ps[t] = s;
  __syncthreads();
  for (int off = 1; off < 1024; off <<= 1) {
    int v = (t >= off) ? ps[t - off] : 0;
    __syncthreads();
    ps[t] += v;
    __syncthreads();
  }
  int run = (t > 0) ? ps[t - 1] : 0;
  for (int i = lo; i < hi; ++i) {
    rowptr[i] = run;
    cursor[i] = run;
    run += cntd[i];
  }
  if (t == 1023) rowptr[NN] = run;
}

// scatter edges into dst-sorted perm: perm[pos] = (src<<3)|rel
__global__ __launch_bounds__(256) void k_scatter(const int* __restrict__ src,
                                                 const int* __restrict__ dst,
                                                 const int* __restrict__ et,
                                                 int* __restrict__ cursor,
                                                 unsigned* __restrict__ perm) {
  int e = blockIdx.x * 256 + threadIdx.x;
  if (e < NE) {
    int pos = atomicAdd(&cursor[dst[e]], 1);
    perm[pos] = ((unsigned)src[e] << 3) | (unsigned)et[e];
  }
}

// ---- layer-1 root: buf1 = x @ root1 + b1 (wave per node) --------------------
__global__ __launch_bounds__(256) void k_root1(const float* __restrict__ x,
                                               const float* __restrict__ root1,
                                               const float* __restrict__ b1,
                                               float* __restrict__ buf1) {
  const int lane = threadIdx.x & 63;
  const int wid  = (blockIdx.x * 256 + (int)threadIdx.x) >> 6;
  const int nw   = gridDim.x * 4;
  float w[64];
#pragma unroll
  for (int f = 0; f < 64; ++f) w[f] = root1[f * 64 + lane];
  const float bl = b1[lane];
  for (int n = wid; n < NN; n += nw) {
    const int xi = __float_as_int(x[n * 64 + lane]);
    float a0 = bl, a1 = 0.f, a2 = 0.f, a3 = 0.f;
#pragma unroll
    for (int f = 0; f < 64; f += 4) {
      a0 = fmaf(bcast(xi, f + 0), w[f + 0], a0);
      a1 = fmaf(bcast(xi, f + 1), w[f + 1], a1);
      a2 = fmaf(bcast(xi, f + 2), w[f + 2], a2);
      a3 = fmaf(bcast(xi, f + 3), w[f + 3], a3);
    }
    buf1[(size_t)n * 64 + lane] = (a0 + a1) + (a2 + a3);
  }
}

// ---- dense h1[r][n][64] = x[n] @ W1[r] --------------------------------------
// block = 4 waves; wave -> one rel (blockIdx.y*4+wid); 64-node tile (blockIdx.x)
// lane = (og 0..7, ng 0..7), 8x8 register micro-tile per lane.
__global__ __launch_bounds__(256) void k_h1(const float* __restrict__ x,
                                            const float* __restrict__ W1,
                                            float* __restrict__ h) {
  __shared__ float xT[64][64];
  const int t  = threadIdx.x;
  const int n0 = blockIdx.x * 64;
  {
    const int lane = t & 63, w = t >> 6;
    const int nl = w * 16 + (lane & 15);  // node-local
    const int q  = lane >> 4;             // feat quarter
    const int n  = n0 + nl;
    float4 v[4];
#pragma unroll
    for (int j = 0; j < 4; ++j) {
      const int f = q * 16 + j * 4;
      if (n < NN) v[j] = *(const float4*)&x[(size_t)n * 64 + f];
      else        v[j] = float4{0.f, 0.f, 0.f, 0.f};
    }
#pragma unroll
    for (int j = 0; j < 4; ++j) {
      const int f = q * 16 + j * 4;
      xT[f + 0][nl] = v[j].x; xT[f + 1][nl] = v[j].y;
      xT[f + 2][nl] = v[j].z; xT[f + 3][nl] = v[j].w;
    }
  }
  __syncthreads();
  const int wid = t >> 6, lane = t & 63;
  const int r  = blockIdx.y * 4 + wid;
  const int og = lane >> 3, ng = lane & 7;
  const float* __restrict__ Wr = W1 + (size_t)r * 4096;
  float acc[8][8];
#pragma unroll
  for (int i = 0; i < 8; ++i)
#pragma unroll
    for (int j = 0; j < 8; ++j) acc[i][j] = 0.f;
#pragma unroll 8
  for (int k = 0; k < 64; ++k) {
    float a[8], b[8];
    *(float4*)&a[0] = *(const float4*)&xT[k][ng * 8];
    *(float4*)&a[4] = *(const float4*)&xT[k][ng * 8 + 4];
    *(float4*)&b[0] = *(const float4*)&Wr[k * 64 + og * 8];
    *(float4*)&b[4] = *(const float4*)&Wr[k * 64 + og * 8 + 4];
#pragma unroll
    for (int i = 0; i < 8; ++i)
#pragma unroll
      for (int j = 0; j < 8; ++j) acc[i][j] = fmaf(a[i], b[j], acc[i][j]);
  }
  float* __restrict__ hr = h + (size_t)r * NN * 64;
#pragma unroll
  for (int i = 0; i < 8; ++i) {
    const int n = n0 + ng * 8 + i;
    if (n < NN) {
      *(float4*)&hr[(size_t)n * 64 + og * 8]     = *(float4*)&acc[i][0];
      *(float4*)&hr[(size_t)n * 64 + og * 8 + 4] = *(float4*)&acc[i][4];
    }
  }
}

// ---- layer-1 aggregate: buf1[n] += sum_e inv[n,rel_e] * h[rel_e][src_e] -----
__global__ __launch_bounds__(256) void k_agg1(const float* __restrict__ h,
                                              const unsigned* __restrict__ perm,
                                              const int* __restrict__ rowptr,
                                              const float* __restrict__ inv,
                                              float* __restrict__ buf1) {
  const int lane = threadIdx.x & 63;
  const int n = blockIdx.x * 4 + ((int)threadIdx.x >> 6);
  if (n >= NN) return;
  const float invv = inv[n * NR + (lane & 7)];
  const int base = rowptr[n], end = rowptr[n + 1];
  float acc = 0.f;
  int i = base;
  for (; i + 1 < end; i += 2) {
    const unsigned p0 = perm[i], p1 = perm[i + 1];
    const float s0 = __shfl(invv, (int)(p0 & 7));
    const float s1 = __shfl(invv, (int)(p1 & 7));
    const float v0 = h[((size_t)(p0 & 7) * NN + (p0 >> 3)) * 64 + lane];
    const float v1 = h[((size_t)(p1 & 7) * NN + (p1 >> 3)) * 64 + lane];
    acc = fmaf(v0, s0, acc);
    acc = fmaf(v1, s1, acc);
  }
  if (i < end) {
    const unsigned p0 = perm[i];
    const float s0 = __shfl(invv, (int)(p0 & 7));
    acc = fmaf(h[((size_t)(p0 & 7) * NN + (p0 >> 3)) * 64 + lane], s0, acc);
  }
  buf1[(size_t)n * 64 + lane] += acc;
}

// ---- layer-2 root: out = relu-less root part: buf1@root2 + b2 ---------------
__global__ __launch_bounds__(256) void k_root2(const float* __restrict__ buf1,
                                               const float* __restrict__ root2,
                                               const float* __restrict__ b2,
                                               float* __restrict__ out) {
  const int lane = threadIdx.x & 63;
  const int o  = lane & 31;
  const int fh = lane >> 5;
  const int wid = (blockIdx.x * 256 + (int)threadIdx.x) >> 6;
  const int nw  = gridDim.x * 4;
  float w[32];
#pragma unroll
  for (int k = 0; k < 32; ++k) w[k] = root2[(fh * 32 + k) * 32 + o];
  const float bo = b2[o];
  for (int n = wid; n < NN; n += nw) {
    const int xi = __float_as_int(fmaxf(buf1[(size_t)n * 64 + lane], 0.f));
    float a0 = 0.f, a1 = 0.f;
#pragma unroll
    for (int k = 0; k < 32; k += 2) {
      float lo0 = bcast(xi, k),     hi0 = bcast(xi, 32 + k);
      float lo1 = bcast(xi, k + 1), hi1 = bcast(xi, 33 + k);
      a0 = fmaf(fh ? hi0 : lo0, w[k], a0);
      a1 = fmaf(fh ? hi1 : lo1, w[k + 1], a1);
    }
    float acc = a0 + a1;
    float oth = __shfl_down(acc, 32);
    if (fh == 0) out[(size_t)n * 32 + o] = acc + oth + bo;
  }
}

// ---- dense h2[r][n][32] = relu(buf1[n]) @ W2[r] -----------------------------
// lane = (og 0..3, ng 0..15), 4x8 micro-tile.
__global__ __launch_bounds__(256) void k_h2(const float* __restrict__ buf1,
                                            const float* __restrict__ W2,
                                            float* __restrict__ h2) {
  __shared__ float xT[64][64];
  const int t  = threadIdx.x;
  const int n0 = blockIdx.x * 64;
  {
    const int lane = t & 63, w = t >> 6;
    const int nl = w * 16 + (lane & 15);
    const int q  = lane >> 4;
    const int n  = n0 + nl;
    float4 v[4];
#pragma unroll
    for (int j = 0; j < 4; ++j) {
      const int f = q * 16 + j * 4;
      if (n < NN) {
        float4 u = *(const float4*)&buf1[(size_t)n * 64 + f];
        v[j] = float4{fmaxf(u.x, 0.f), fmaxf(u.y, 0.f), fmaxf(u.z, 0.f), fmaxf(u.w, 0.f)};
      } else v[j] = float4{0.f, 0.f, 0.f, 0.f};
    }
#pragma unroll
    for (int j = 0; j < 4; ++j) {
      const int f = q * 16 + j * 4;
      xT[f + 0][nl] = v[j].x; xT[f + 1][nl] = v[j].y;
      xT[f + 2][nl] = v[j].z; xT[f + 3][nl] = v[j].w;
    }
  }
  __syncthreads();
  const int wid = t >> 6, lane = t & 63;
  const int r  = blockIdx.y * 4 + wid;
  const int og = lane >> 4, ng = lane & 15;
  const float* __restrict__ Wr = W2 + (size_t)r * 2048;
  float acc[4][8];
#pragma unroll
  for (int i = 0; i < 4; ++i)
#pragma unroll
    for (int j = 0; j < 8; ++j) acc[i][j] = 0.f;
#pragma unroll 8
  for (int k = 0; k < 64; ++k) {
    float a[4], b[8];
    *(float4*)&a[0] = *(const float4*)&xT[k][ng * 4];
    *(float4*)&b[0] = *(const float4*)&Wr[k * 32 + og * 8];
    *(float4*)&b[4] = *(const float4*)&Wr[k * 32 + og * 8 + 4];
#pragma unroll
    for (int i = 0; i < 4; ++i)
#pragma unroll
      for (int j = 0; j < 8; ++j) acc[i][j] = fmaf(a[i], b[j], acc[i][j]);
  }
  float* __restrict__ hr = h2 + (size_t)r * NN * 32;
#pragma unroll
  for (int i = 0; i < 4; ++i) {
    const int n = n0 + ng * 4 + i;
    if (n < NN) {
      *(float4*)&hr[(size_t)n * 32 + og * 8]     = *(float4*)&acc[i][0];
      *(float4*)&hr[(size_t)n * 32 + og * 8 + 4] = *(float4*)&acc[i][4];
    }
  }
}

// ---- layer-2 aggregate: out[n] += sum_e inv * h2[rel_e][src_e] --------------
// half-wave per edge (32 feats), 2 edges per iteration.
__global__ __launch_bounds__(256) void k_agg2(const float* __restrict__ h2,
                                              const unsigned* __restrict__ perm,
                                              const int* __restrict__ rowptr,
                                              const float* __restrict__ inv,
                                              float* __restrict__ out) {
  const int lane = threadIdx.x & 63;
  const int o = lane & 31, eh = lane >> 5;
  const int n = blockIdx.x * 4 + ((int)threadIdx.x >> 6);
  if (n >= NN) return;
  const float invv = inv[n * NR + (lane & 7)];
  const int base = rowptr[n], end = rowptr[n + 1];
  float acc = 0.f;
  for (int i = base; i < end; i += 2) {
    const int i0 = i + eh;
    const bool val = i0 < end;
    const unsigned p = perm[val ? i0 : i];
    float s = __shfl(invv, (int)(p & 7));
    if (!val) s = 0.f;
    acc = fmaf(h2[((size_t)(p & 7) * NN + (p >> 3)) * 32 + o], s, acc);
  }
  acc += __shfl_down(acc, 32);
  if (eh == 0) out[(size_t)n * 32 + o] += acc;
}

// ================= fallback (R1) path, used when ws is small =================
__global__ __launch_bounds__(256) void k_inv_fb(int* __restrict__ cnt) {
  int i = blockIdx.x * 256 + threadIdx.x;
  if (i < NN * NR) {
    int c = cnt[i];
    ((float*)cnt)[i] = 1.0f / (float)(c < 1 ? 1 : c);
  }
}

__global__ __launch_bounds__(256) void k_edge1(const float* __restrict__ x,
                                               const int* __restrict__ ei,
                                               const int* __restrict__ et,
                                               const float* __restrict__ W1,
                                               const float* __restrict__ inv,
                                               float* __restrict__ buf1) {
  const int r    = blockIdx.y;
  const int lane = threadIdx.x & 63;
  float w[64];
#pragma unroll
  for (int f = 0; f < 64; ++f) w[f] = W1[r * 4096 + f * 64 + lane];
  const int* __restrict__ srcA = ei;
  const int* __restrict__ dstA = ei + NE;
  const int wir = blockIdx.x * 4 + ((int)threadIdx.x >> 6);
  const int wpr = gridDim.x * 4;
  const int nch = (NE + 63) >> 6;
  for (int c = wir; c < nch; c += wpr) {
    const int e = c * 64 + lane;
    int sv = 0, dv = 0, tv = -1;
    if (e < NE) { sv = srcA[e]; dv = dstA[e]; tv = et[e]; }
    unsigned long long m = __ballot(tv == r);
    while (m) {
      const int i = __builtin_ctzll(m);
      m &= m - 1;
      const int s = __builtin_amdgcn_readlane(sv, i);
      const int d = __builtin_amdgcn_readlane(dv, i);
      const int xi = __float_as_int(x[s * 64 + lane]);
      float a0 = 0.f, a1 = 0.f, a2 = 0.f, a3 = 0.f;
#pragma unroll
      for (int f = 0; f < 64; f += 4) {
        a0 = fmaf(bcast(xi, f + 0), w[f + 0], a0);
        a1 = fmaf(bcast(xi, f + 1), w[f + 1], a1);
        a2 = fmaf(bcast(xi, f + 2), w[f + 2], a2);
        a3 = fmaf(bcast(xi, f + 3), w[f + 3], a3);
      }
      const float sc = inv[d * NR + r];
      atomicAdd(&buf1[d * 64 + lane], ((a0 + a1) + (a2 + a3)) * sc);
    }
  }
}

__global__ __launch_bounds__(256) void k_edge2(const float* __restrict__ buf1,
                                               const int* __restrict__ ei,
                                               const int* __restrict__ et,
                                               const float* __restrict__ W2,
                                               const float* __restrict__ inv,
                                               float* __restrict__ out) {
  const int r    = blockIdx.y;
  const int lane = threadIdx.x & 63;
  const int o  = lane & 31;
  const int fh = lane >> 5;
  float w[32];
#pragma unroll
  for (int k = 0; k < 32; ++k) w[k] = W2[r * 2048 + (fh * 32 + k) * 32 + o];
  const int* __restrict__ srcA = ei;
  const int* __restrict__ dstA = ei + NE;
  const int wir = blockIdx.x * 4 + ((int)threadIdx.x >> 6);
  const int wpr = gridDim.x * 4;
  const int nch = (NE + 63) >> 6;
  for (int c = wir; c < nch; c += wpr) {
    const int e = c * 64 + lane;
    int sv = 0, dv = 0, tv = -1;
    if (e < NE) { sv = srcA[e]; dv = dstA[e]; tv = et[e]; }
    unsigned long long m = __ballot(tv == r);
    while (m) {
      const int i = __builtin_ctzll(m);
      m &= m - 1;
      const int s = __builtin_amdgcn_readlane(sv, i);
      const int d = __builtin_amdgcn_readlane(dv, i);
      const int xi = __float_as_int(fmaxf(buf1[s * 64 + lane], 0.f));
      float a0 = 0.f, a1 = 0.f;
#pragma unroll
      for (int k = 0; k < 32; k += 2) {
        float lo0 = bcast(xi, k),     hi0 = bcast(xi, 32 + k);
        float lo1 = bcast(xi, k + 1), hi1 = bcast(xi, 33 + k);
        a0 = fmaf(fh ? hi0 : lo0, w[k], a0);
        a1 = fmaf(fh ? hi1 : lo1, w[k + 1], a1);
      }
      float acc = a0 + a1;
      float oth = __shfl_down(acc, 32);
      if (fh == 0) {
        const float sc = inv[d * NR + r];
        atomicAdd(&out[d * 32 + o], (acc + oth) * sc);
      }
    }
  }
}

// =============================================================================
extern "C" void kernel_launch(void* const* d_in, const int* in_sizes, int n_in,
                              void* d_out, int out_size, void* d_ws, size_t ws_size,
                              hipStream_t stream) {
  const float* x     = (const float*)d_in[0];
  const int*   ei    = (const int*)d_in[1];
  const int*   et    = (const int*)d_in[2];
  const float* W1    = (const float*)d_in[3];
  const float* root1 = (const float*)d_in[4];
  const float* b1    = (const float*)d_in[5];
  const float* W2    = (const float*)d_in[6];
  const float* root2 = (const float*)d_in[7];
  const float* b2    = (const float*)d_in[8];
  float* out = (float*)d_out;
  const int* srcA = ei;
  const int* dstA = ei + NE;

  // ws layout (fast path)
  char* w = (char*)d_ws;
  size_t off = 0;
  int*      cnt    = (int*)(w + off);      off += (size_t)NN * NR * 4;   // 1.6MB
  float*    inv    = (float*)cnt;
  int*      cntd   = (int*)(w + off);      off += (size_t)NN * 4;
  int*      rowptr = (int*)(w + off);      off += (size_t)(NN + 1) * 4;
  int*      cursor = (int*)(w + off);      off += (size_t)NN * 4;
  unsigned* perm   = (unsigned*)(w + off); off += (size_t)NE * 4;        // 3.2MB
  off = (off + 15) & ~(size_t)15;
  float*    buf1   = (float*)(w + off);    off += (size_t)NN * 64 * 4;   // 12.8MB
  off = (off + 15) & ~(size_t)15;
  float*    h      = (float*)(w + off);    off += (size_t)NR * NN * 64 * 4; // 102.4MB
  const size_t REQ = off;

  if (ws_size >= REQ) {
    hipMemsetAsync(cnt, 0, (size_t)NN * NR * 4, stream);
    k_hist<<<(NE + 255) / 256, 256, 0, stream>>>(dstA, et, cnt);
    k_inv2<<<(NN + 255) / 256, 256, 0, stream>>>(cnt, cntd);
    k_scan<<<1, 1024, 0, stream>>>(cntd, rowptr, cursor);
    k_scatter<<<(NE + 255) / 256, 256, 0, stream>>>(srcA, dstA, et, cursor, perm);
    k_root1<<<1024, 256, 0, stream>>>(x, root1, b1, buf1);
    k_h1<<<dim3((NN + 63) / 64, 2), 256, 0, stream>>>(x, W1, h);
    k_agg1<<<(NN + 3) / 4, 256, 0, stream>>>(h, perm, rowptr, inv, buf1);
    k_root2<<<512, 256, 0, stream>>>(buf1, root2, b2, out);
    k_h2<<<dim3((NN + 63) / 64, 2), 256, 0, stream>>>(buf1, W2, h);  // reuse h
    k_agg2<<<(NN + 3) / 4, 256, 0, stream>>>(h, perm, rowptr, inv, out);
  } else {
    // fallback: R1 path (14.4MB ws)
    int*   fcnt  = (int*)d_ws;
    float* finv  = (float*)d_ws;
    float* fbuf1 = (float*)((char*)d_ws + (size_t)NN * NR * 4);
    hipMemsetAsync(fcnt, 0, (size_t)NN * NR * 4, stream);
    k_hist<<<(NE + 255) / 256, 256, 0, stream>>>(dstA, et, fcnt);
    k_inv_fb<<<(NN * NR + 255) / 256, 256, 0, stream>>>(fcnt);
    k_root1<<<1024, 256, 0, stream>>>(x, root1, b1, fbuf1);
    k_edge1<<<dim3(128, NR), 256, 0, stream>>>(x, ei, et, W1, finv, fbuf1);
    k_root2<<<512, 256, 0, stream>>>(fbuf1, root2, b2, out);
    k_edge2<<<dim3(128, NR), 256, 0, stream>>>(fbuf1, ei, et, W2, finv, out);
  }
}

// Round 3
// 452.303 us; speedup vs baseline: 1.8281x; 1.1406x over previous
//
#include <hip/hip_runtime.h>

// RGCN 2-layer: N=50000, E=800000, R=8, 64->64->32, fp32.
// R3 structure: aggregate-then-transform.
//   memset(seg) -> hist(per (dst,rel) counts) -> 3-phase parallel scan ->
//   scatter (edges sorted by (dst,rel), perm[pos]=src) ->
//   gath1: A[n, r*64+f] = inv(n,r) * sum_e x[src]   (random reads hit 12.8MB x)
//   gemm1: buf1 = [A | x] @ vstack(W1, root1) + b1  (root = 9th K-tile)
//   gath2: A from relu(buf1)
//   gemm2: out = [A | relu(buf1)] @ vstack(W2, root2) + b2
// ws ~120MB (<= R2's proven 120.65MB).

#define NN 50000
#define NE 800000
#define NR 8
#define NPR (NN * NR)              // 400000 segments
#define NBLK ((NPR + 1023) / 1024) // 391 scan blocks

// ---- per-(dst,rel) incoming-edge count into seg[] ---------------------------
__global__ __launch_bounds__(256) void k_hist(const int* __restrict__ dst,
                                              const int* __restrict__ et,
                                              int* __restrict__ seg) {
  int e = blockIdx.x * 256 + threadIdx.x;
  if (e < NE) atomicAdd(&seg[dst[e] * NR + et[e]], 1);
}

// ---- 3-phase exclusive scan of seg[NPR] (in place) --------------------------
__global__ __launch_bounds__(256) void k_scanA(const int* __restrict__ seg,
                                               int* __restrict__ bsum) {
  __shared__ int red[256];
  const int t = threadIdx.x;
  const int base = blockIdx.x * 1024 + t * 4;
  int s = 0;
#pragma unroll
  for (int j = 0; j < 4; ++j)
    if (base + j < NPR) s += seg[base + j];
  red[t] = s;
  __syncthreads();
  for (int off = 128; off > 0; off >>= 1) {
    if (t < off) red[t] += red[t + off];
    __syncthreads();
  }
  if (t == 0) bsum[blockIdx.x] = red[0];
}

__global__ __launch_bounds__(512) void k_scanB(const int* __restrict__ bsum,
                                               int* __restrict__ boff) {
  __shared__ int ps[512];
  const int t = threadIdx.x;
  const int v = (t < NBLK) ? bsum[t] : 0;
  ps[t] = v;
  __syncthreads();
  for (int off = 1; off < 512; off <<= 1) {
    int u = (t >= off) ? ps[t - off] : 0;
    __syncthreads();
    ps[t] += u;
    __syncthreads();
  }
  if (t < NBLK) boff[t] = ps[t] - v;  // exclusive
}

__global__ __launch_bounds__(256) void k_scanC(int* __restrict__ seg,
                                               const int* __restrict__ boff) {
  __shared__ int ps[256];
  const int t = threadIdx.x;
  const int base = blockIdx.x * 1024 + t * 4;
  int v[4];
  int s = 0;
#pragma unroll
  for (int j = 0; j < 4; ++j) {
    v[j] = (base + j < NPR) ? seg[base + j] : 0;
    s += v[j];
  }
  ps[t] = s;
  __syncthreads();
  for (int off = 1; off < 256; off <<= 1) {
    int u = (t >= off) ? ps[t - off] : 0;
    __syncthreads();
    ps[t] += u;
    __syncthreads();
  }
  int run = ps[t] - s + boff[blockIdx.x];
#pragma unroll
  for (int j = 0; j < 4; ++j) {
    if (base + j < NPR) {
      int old = v[j];
      seg[base + j] = run;  // exclusive prefix
      run += old;
    }
  }
}

// ---- scatter: perm sorted by (dst,rel); seg becomes inclusive segment ends --
__global__ __launch_bounds__(256) void k_scatter(const int* __restrict__ src,
                                                 const int* __restrict__ dst,
                                                 const int* __restrict__ et,
                                                 int* __restrict__ seg,
                                                 int* __restrict__ perm) {
  int e = blockIdx.x * 256 + threadIdx.x;
  if (e < NE) {
    int pos = atomicAdd(&seg[dst[e] * NR + et[e]], 1);
    perm[pos] = src[e];
  }
}

// ---- gather: A[n, r*64+lane] = inv(n,r) * sum_{e in seg(n,r)} feat[src] -----
// wave per node; segment start = seg[idx-1] (post-scatter ends), end = seg[idx].
template <bool RELU>
__global__ __launch_bounds__(256) void k_gath(const float* __restrict__ feat,
                                              const int* __restrict__ perm,
                                              const int* __restrict__ seg,
                                              float* __restrict__ A) {
  const int lane = threadIdx.x & 63;
  const int n = blockIdx.x * 4 + ((int)threadIdx.x >> 6);
  if (n >= NN) return;
  float* __restrict__ Arow = A + (size_t)n * 512 + lane;
  const int idx0 = n * NR;
#pragma unroll
  for (int r = 0; r < NR; ++r) {
    const int s0 = (idx0 + r == 0) ? 0 : seg[idx0 + r - 1];
    const int e0 = seg[idx0 + r];
    float a0 = 0.f, a1 = 0.f;
    int i = s0;
    for (; i + 1 < e0; i += 2) {
      const int p0 = perm[i], p1 = perm[i + 1];
      float v0 = feat[(size_t)p0 * 64 + lane];
      float v1 = feat[(size_t)p1 * 64 + lane];
      if (RELU) { v0 = fmaxf(v0, 0.f); v1 = fmaxf(v1, 0.f); }
      a0 += v0;
      a1 += v1;
    }
    if (i < e0) {
      float v = feat[(size_t)perm[i] * 64 + lane];
      if (RELU) v = fmaxf(v, 0.f);
      a0 += v;
    }
    const int c = e0 - s0;
    const float invc = 1.0f / (float)(c < 1 ? 1 : c);
    Arow[r * 64] = (a0 + a1) * invc;
  }
}

// ---- GEMM: C[50k x TN] = A[50k x 512] @ W[512 x TN]
//            + rootsrc[50k x 64] (opt. relu) @ root[64 x TN] + bias -----------
// 64xTN tile per block, 256 threads, 16 fma/thread/k (TN=64) in 4x(TN/16) micro.
// As stored [k][m] padded to 68 (16B-aligned rows, conflict-free b128 reads).
template <int TN, bool RELU_ROOT>
__global__ __launch_bounds__(256) void k_gemm(const float* __restrict__ A,
                                              const float* __restrict__ rootsrc,
                                              const float* __restrict__ W,
                                              const float* __restrict__ root,
                                              const float* __restrict__ bias,
                                              float* __restrict__ C) {
  __shared__ float As[64][68];
  __shared__ float Bs[64][TN];
  const int tid = threadIdx.x;
  const int n0 = blockIdx.x * 64;
  const int ty = tid >> 4, tx = tid & 15;
  constexpr int JW = TN / 16;  // 4 (TN=64) or 2 (TN=32)
  float acc[4][JW];
#pragma unroll
  for (int i = 0; i < 4; ++i)
#pragma unroll
    for (int j = 0; j < JW; ++j) acc[i][j] = 0.f;

  for (int kt = 0; kt < 9; ++kt) {
    // ---- stage A-tile (transposed: As[k][m]) ----
    {
      const int mb = tid >> 4;   // 0..15 (+pass*16)
      const int lf = tid & 15;   // 4-float chunk along k
#pragma unroll
      for (int pass = 0; pass < 4; ++pass) {
        const int mm = mb + pass * 16;
        const int n = n0 + mm;
        float4 v = {0.f, 0.f, 0.f, 0.f};
        if (n < NN) {
          if (kt < 8) {
            v = *(const float4*)&A[(size_t)n * 512 + kt * 64 + lf * 4];
          } else {
            v = *(const float4*)&rootsrc[(size_t)n * 64 + lf * 4];
            if (RELU_ROOT) {
              v.x = fmaxf(v.x, 0.f); v.y = fmaxf(v.y, 0.f);
              v.z = fmaxf(v.z, 0.f); v.w = fmaxf(v.w, 0.f);
            }
          }
        }
        As[lf * 4 + 0][mm] = v.x;
        As[lf * 4 + 1][mm] = v.y;
        As[lf * 4 + 2][mm] = v.z;
        As[lf * 4 + 3][mm] = v.w;
      }
    }
    // ---- stage B-tile ----
    {
      const float* __restrict__ Bsrc = (kt < 8) ? (W + (size_t)kt * 64 * TN) : root;
      if (TN == 64) {
        const int kr = tid >> 4, lf = tid & 15;
#pragma unroll
        for (int pass = 0; pass < 4; ++pass) {
          const int k = kr + pass * 16;
          *(float4*)&Bs[k][lf * 4] = *(const float4*)&Bsrc[k * TN + lf * 4];
        }
      } else {
        const int kr = tid >> 3, lf = tid & 7;
#pragma unroll
        for (int pass = 0; pass < 2; ++pass) {
          const int k = kr + pass * 32;
          *(float4*)&Bs[k][lf * 4] = *(const float4*)&Bsrc[k * TN + lf * 4];
        }
      }
    }
    __syncthreads();
#pragma unroll 8
    for (int k = 0; k < 64; ++k) {
      const float4 a = *(const float4*)&As[k][ty * 4];
      float b[JW];
      if (TN == 64) {
        *(float4*)&b[0] = *(const float4*)&Bs[k][tx * 4];
      } else {
        *(float2*)&b[0] = *(const float2*)&Bs[k][tx * 2];
      }
      const float av[4] = {a.x, a.y, a.z, a.w};
#pragma unroll
      for (int i = 0; i < 4; ++i)
#pragma unroll
        for (int j = 0; j < JW; ++j) acc[i][j] = fmaf(av[i], b[j], acc[i][j]);
    }
    __syncthreads();
  }
  // ---- epilogue: + bias, store ----
  float bv[JW];
#pragma unroll
  for (int j = 0; j < JW; ++j) bv[j] = bias[tx * JW + j];
#pragma unroll
  for (int i = 0; i < 4; ++i) {
    const int n = n0 + ty * 4 + i;
    if (n < NN) {
#pragma unroll
      for (int j = 0; j < JW; ++j)
        C[(size_t)n * TN + tx * JW + j] = acc[i][j] + bv[j];
    }
  }
}

// =============================================================================
extern "C" void kernel_launch(void* const* d_in, const int* in_sizes, int n_in,
                              void* d_out, int out_size, void* d_ws, size_t ws_size,
                              hipStream_t stream) {
  const float* x     = (const float*)d_in[0];
  const int*   ei    = (const int*)d_in[1];
  const int*   et    = (const int*)d_in[2];
  const float* W1    = (const float*)d_in[3];
  const float* root1 = (const float*)d_in[4];
  const float* b1    = (const float*)d_in[5];
  const float* W2    = (const float*)d_in[6];
  const float* root2 = (const float*)d_in[7];
  const float* b2    = (const float*)d_in[8];
  float* out = (float*)d_out;
  const int* srcA = ei;
  const int* dstA = ei + NE;

  // ws layout
  char* w = (char*)d_ws;
  size_t off = 0;
  int* seg  = (int*)(w + off); off += (size_t)NPR * 4;        // 1.6MB
  int* bsum = (int*)(w + off); off += (size_t)NBLK * 4;
  int* boff = (int*)(w + off); off += (size_t)NBLK * 4;
  int* perm = (int*)(w + off); off += (size_t)NE * 4;         // 3.2MB
  off = (off + 15) & ~(size_t)15;
  float* buf1 = (float*)(w + off); off += (size_t)NN * 64 * 4;   // 12.8MB
  off = (off + 15) & ~(size_t)15;
  float* A = (float*)(w + off); off += (size_t)NN * 512 * 4;     // 102.4MB

  hipMemsetAsync(seg, 0, (size_t)NPR * 4, stream);
  k_hist<<<(NE + 255) / 256, 256, 0, stream>>>(dstA, et, seg);
  k_scanA<<<NBLK, 256, 0, stream>>>(seg, bsum);
  k_scanB<<<1, 512, 0, stream>>>(bsum, boff);
  k_scanC<<<NBLK, 256, 0, stream>>>(seg, boff);
  k_scatter<<<(NE + 255) / 256, 256, 0, stream>>>(srcA, dstA, et, seg, perm);

  k_gath<false><<<(NN + 3) / 4, 256, 0, stream>>>(x, perm, seg, A);
  k_gemm<64, false><<<(NN + 63) / 64, 256, 0, stream>>>(A, x, W1, root1, b1, buf1);
  k_gath<true><<<(NN + 3) / 4, 256, 0, stream>>>(buf1, perm, seg, A);
  k_gemm<32, true><<<(NN + 63) / 64, 256, 0, stream>>>(A, buf1, W2, root2, b2, out);
}